// Round 4
// baseline (166.304 us; speedup 1.0000x reference)
//
#include <hip/hip_runtime.h>

#define BATCH 4096
#define SEQT  512
#define HID   32
#define WPB   4      // waves per block
#define ROWF  36     // padded hist row stride in f32 units (144 B)

typedef float f32x2 __attribute__((ext_vector_type(2)));

#define FMA2(a, b, c) __builtin_elementwise_fma((a), (b), (c))

#if __has_builtin(__builtin_amdgcn_exp2f)
#define FAST_EXP2(x) __builtin_amdgcn_exp2f(x)
#else
#define FAST_EXP2(x) exp2f(x)
#endif
#if __has_builtin(__builtin_amdgcn_rcpf)
#define FAST_RCP(x) __builtin_amdgcn_rcpf(x)
#else
#define FAST_RCP(x) (1.0f / (x))
#endif

// DPP lane-xor controls (all stay within a 16-lane row => within a seq group)
#define DPP_X1  0xB1   // quad_perm [1,0,3,2] : lane ^= 1
#define DPP_X2  0x4E   // quad_perm [2,3,0,1] : lane ^= 2
#define DPP_X7  0x141  // row_half_mirror     : lane ^= 7
#define DPP_X15 0x140  // row_mirror          : lane ^= 15

#if __has_builtin(__builtin_amdgcn_mov_dpp)
#define XLI(x, C) __builtin_amdgcn_mov_dpp((x), (C), 0xF, 0xF, false)
#elif __has_builtin(__builtin_amdgcn_update_dpp)
#define XLI(x, C) __builtin_amdgcn_update_dpp(0, (x), (C), 0xF, 0xF, false)
#else
#define XLI(x, C) __shfl_xor((x), ((C) == DPP_X1) ? 1 : ((C) == DPP_X2) ? 2 : ((C) == DPP_X7) ? 7 : 15)
#endif

template <int C>
__device__ __forceinline__ f32x2 xl2(f32x2 v) {
    union { f32x2 f; int i[2]; } u, r;
    u.f = v;
    r.i[0] = XLI(u.i[0], C);
    r.i[1] = XLI(u.i[1], C);
    return r.f;
}

__device__ __forceinline__ f32x2 lo2(float4 q) { f32x2 r; r.x = q.x; r.y = q.y; return r; }
__device__ __forceinline__ f32x2 hi2(float4 q) { f32x2 r; r.x = q.z; r.y = q.w; return r; }

// 16 lanes per sequence; lane ell owns h-pair (h[2*ell], h[2*ell+1]) as a
// float2 (FULL f32 state -- no f16 quantization). Per step: 30 DPP movs
// all-gather the 16 float2 pairs (reg r holds pair ell ^ MTBL[r]; W_hh regs
// permuted per-lane at init to match), then 32 v_pk_fma_f32 compute both
// output rows, tanh, done. The recurrence has NO LDS reads, no barriers, no
// waitcnt. h history is dribbled to LDS via fire-and-forget ds_write_b64;
// the Linear(32->1) output is a chunk-end pass (lane = t-index) amortized to
// ~2 instr/step, off the recurrence dependency chain entirely.
__global__ __launch_bounds__(64 * WPB, 1) void rnn_kernel(
    const float* __restrict__ x,      // [B, T]
    const float* __restrict__ h0,     // [B, H]
    const float* __restrict__ W_ih,   // [H]
    const float* __restrict__ b_ih,   // [H]
    const float* __restrict__ W_hh,   // [H, H] row-major
    const float* __restrict__ b_hh,   // [H]
    const float* __restrict__ W_out,  // [H]
    const float* __restrict__ b_out,  // [1]
    float* __restrict__ out)          // [B*T] outs, then [B*H] hT
{
    const int tid  = threadIdx.x;
    const int wv   = tid >> 6;
    const int lane = tid & 63;
    const int g    = lane >> 4;                      // seq-in-wave (4 per wave)
    const int ell  = lane & 15;                      // lane within seq group
    const int bseq = blockIdx.x * (4 * WPB) + wv * 4 + g;
    const int j0 = 2 * ell, j1 = 2 * ell + 1;        // owned hidden rows

    __shared__ float hist_s[WPB][4][16][ROWF];       // [wave][seq][t][32h + pad]

    // gather-reg r holds pair (ell ^ MTBL[r]) after the DPP rounds below
    constexpr int MTBL[16] = {0, 1, 2, 3, 7, 6, 5, 4, 15, 14, 13, 12, 8, 9, 10, 11};

    // ---- W_hh rows j0/j1 as f32 pairs, permuted to match gather order ----
    f32x2 W0[16], W1[16];
    #pragma unroll
    for (int r = 0; r < 16; ++r) {
        const int p = ell ^ MTBL[r];
        W0[r] = *reinterpret_cast<const f32x2*>(W_hh + j0 * HID + 2 * p);
        W1[r] = *reinterpret_cast<const f32x2*>(W_hh + j1 * HID + 2 * p);
    }
    // ---- W_out as f32 pairs, natural order (out-pass is not permuted) ----
    f32x2 Wo[16];
    #pragma unroll
    for (int r = 0; r < 16; ++r)
        Wo[r] = *reinterpret_cast<const f32x2*>(W_out + 2 * r);

    const float wih0 = W_ih[j0], wih1 = W_ih[j1];
    const float bia0 = b_ih[j0] + b_hh[j0];
    const float bia1 = b_ih[j1] + b_hh[j1];
    const float bout = b_out[0];
    const f32x2 Z2 = {0.0f, 0.0f};

    // seed h_{-1}
    f32x2 hcur = *reinterpret_cast<const f32x2*>(h0 + (size_t)bseq * HID + j0);

    const float* xg = x + (size_t)bseq * SEQT;
    float*       og = out + (size_t)bseq * SEQT;
    float*       hlane = &hist_s[wv][g][0][2 * ell];   // + t*ROWF per step

#define STEP(T2, XC) do {                                                     \
    f32x2 v0 = hcur;                                                          \
    f32x2 v1 = xl2<DPP_X1>(v0);                                               \
    f32x2 v2 = xl2<DPP_X2>(v0);                                               \
    f32x2 v3 = xl2<DPP_X2>(v1);                                               \
    f32x2 v4 = xl2<DPP_X7>(v0);                                               \
    f32x2 v5 = xl2<DPP_X7>(v1);                                               \
    f32x2 v6 = xl2<DPP_X7>(v2);                                               \
    f32x2 v7 = xl2<DPP_X7>(v3);                                               \
    f32x2 v8  = xl2<DPP_X15>(v0);                                             \
    f32x2 v9  = xl2<DPP_X15>(v1);                                             \
    f32x2 v10 = xl2<DPP_X15>(v2);                                             \
    f32x2 v11 = xl2<DPP_X15>(v3);                                             \
    f32x2 v12 = xl2<DPP_X15>(v4);                                             \
    f32x2 v13 = xl2<DPP_X15>(v5);                                             \
    f32x2 v14 = xl2<DPP_X15>(v6);                                             \
    f32x2 v15 = xl2<DPP_X15>(v7);                                             \
    f32x2 A0; A0.x = fmaf((XC), wih0, bia0); A0.y = 0.0f;                     \
    f32x2 B0; B0.x = fmaf((XC), wih1, bia1); B0.y = 0.0f;                     \
    A0 = FMA2(v0, W0[0], A0);                                                 \
    f32x2 A1 = FMA2(v1, W0[1], Z2);                                           \
    f32x2 A2 = FMA2(v2, W0[2], Z2);                                           \
    f32x2 A3 = FMA2(v3, W0[3], Z2);                                           \
    A0 = FMA2(v4,  W0[4],  A0); A1 = FMA2(v5,  W0[5],  A1);                   \
    A2 = FMA2(v6,  W0[6],  A2); A3 = FMA2(v7,  W0[7],  A3);                   \
    A0 = FMA2(v8,  W0[8],  A0); A1 = FMA2(v9,  W0[9],  A1);                   \
    A2 = FMA2(v10, W0[10], A2); A3 = FMA2(v11, W0[11], A3);                   \
    A0 = FMA2(v12, W0[12], A0); A1 = FMA2(v13, W0[13], A1);                   \
    A2 = FMA2(v14, W0[14], A2); A3 = FMA2(v15, W0[15], A3);                   \
    B0 = FMA2(v0, W1[0], B0);                                                 \
    f32x2 B1 = FMA2(v1, W1[1], Z2);                                           \
    f32x2 B2 = FMA2(v2, W1[2], Z2);                                           \
    f32x2 B3 = FMA2(v3, W1[3], Z2);                                           \
    B0 = FMA2(v4,  W1[4],  B0); B1 = FMA2(v5,  W1[5],  B1);                   \
    B2 = FMA2(v6,  W1[6],  B2); B3 = FMA2(v7,  W1[7],  B3);                   \
    B0 = FMA2(v8,  W1[8],  B0); B1 = FMA2(v9,  W1[9],  B1);                   \
    B2 = FMA2(v10, W1[10], B2); B3 = FMA2(v11, W1[11], B3);                   \
    B0 = FMA2(v12, W1[12], B0); B1 = FMA2(v13, W1[13], B1);                   \
    B2 = FMA2(v14, W1[14], B2); B3 = FMA2(v15, W1[15], B3);                   \
    const f32x2 As = (A0 + A1) + (A2 + A3);                                   \
    const f32x2 Bs = (B0 + B1) + (B2 + B3);                                   \
    const float s0 = As.x + As.y;                                             \
    const float s1 = Bs.x + Bs.y;                                             \
    const float e0 = FAST_EXP2(s0 * 2.8853900817779268f);                     \
    const float e1 = FAST_EXP2(s1 * 2.8853900817779268f);                     \
    f32x2 hc2;                                                                \
    hc2.x = fmaf(-2.0f, FAST_RCP(e0 + 1.0f), 1.0f);                           \
    hc2.y = fmaf(-2.0f, FAST_RCP(e1 + 1.0f), 1.0f);                           \
    hcur = hc2;                                                               \
    *reinterpret_cast<f32x2*>(hlane + (T2) * ROWF) = hcur;                    \
} while (0)

#define HALF(HC, Q0, Q1, Q2, Q3) do {                                         \
    STEP(0,  (Q0).x); STEP(1,  (Q0).y); STEP(2,  (Q0).z); STEP(3,  (Q0).w);   \
    STEP(4,  (Q1).x); STEP(5,  (Q1).y); STEP(6,  (Q1).z); STEP(7,  (Q1).w);   \
    STEP(8,  (Q2).x); STEP(9,  (Q2).y); STEP(10, (Q2).z); STEP(11, (Q2).w);   \
    STEP(12, (Q3).x); STEP(13, (Q3).y); STEP(14, (Q3).z); STEP(15, (Q3).w);   \
    __builtin_amdgcn_wave_barrier();                                          \
    {   /* chunk-end output pass: lane ell = t-index within this half */      \
        const float4* rp = reinterpret_cast<const float4*>(&hist_s[wv][g][ell][0]); \
        const float4 q0 = rp[0], q1 = rp[1], q2 = rp[2], q3 = rp[3];          \
        const float4 q4 = rp[4], q5 = rp[5], q6 = rp[6], q7 = rp[7];          \
        f32x2 o0 = FMA2(lo2(q0), Wo[0],  Z2);                                 \
        f32x2 o1 = FMA2(hi2(q0), Wo[1],  Z2);                                 \
        f32x2 o2 = FMA2(lo2(q1), Wo[2],  Z2);                                 \
        f32x2 o3 = FMA2(hi2(q1), Wo[3],  Z2);                                 \
        o0 = FMA2(lo2(q2), Wo[4],  o0); o1 = FMA2(hi2(q2), Wo[5],  o1);       \
        o2 = FMA2(lo2(q3), Wo[6],  o2); o3 = FMA2(hi2(q3), Wo[7],  o3);       \
        o0 = FMA2(lo2(q4), Wo[8],  o0); o1 = FMA2(hi2(q4), Wo[9],  o1);       \
        o2 = FMA2(lo2(q5), Wo[10], o2); o3 = FMA2(hi2(q5), Wo[11], o3);       \
        o0 = FMA2(lo2(q6), Wo[12], o0); o1 = FMA2(hi2(q6), Wo[13], o1);       \
        o2 = FMA2(lo2(q7), Wo[14], o2); o3 = FMA2(hi2(q7), Wo[15], o3);       \
        const f32x2 os = (o0 + o1) + (o2 + o3);                               \
        og[(HC) * 16 + ell] = os.x + os.y + bout;                             \
    }                                                                         \
    __builtin_amdgcn_wave_barrier();                                          \
} while (0)

    // x register double-buffer: 16 steps (4x float4) per half-chunk
    const float4* xq0 = reinterpret_cast<const float4*>(xg);
    float4 qA0 = xq0[0], qA1 = xq0[1], qA2 = xq0[2], qA3 = xq0[3];
    float4 qB0, qB1, qB2, qB3;

    #pragma unroll 1
    for (int hc = 0; hc < 32; hc += 2) {
        const float4* pB = reinterpret_cast<const float4*>(xg + (hc + 1) * 16);
        qB0 = pB[0]; qB1 = pB[1]; qB2 = pB[2]; qB3 = pB[3];
        HALF(hc, qA0, qA1, qA2, qA3);
        const int tn = (hc + 2 < 32) ? (hc + 2) : 0;  // clamp: harmless reload
        const float4* pA = reinterpret_cast<const float4*>(xg + tn * 16);
        qA0 = pA[0]; qA1 = pA[1]; qA2 = pA[2]; qA3 = pA[3];
        HALF(hc + 1, qB0, qB1, qB2, qB3);
    }

    // final hidden state [1, B, H]
    *reinterpret_cast<f32x2*>(out + (size_t)BATCH * SEQT + (size_t)bseq * HID + j0) = hcur;

#undef HALF
#undef STEP
}

extern "C" void kernel_launch(void* const* d_in, const int* in_sizes, int n_in,
                              void* d_out, int out_size, void* d_ws, size_t ws_size,
                              hipStream_t stream) {
    const float* x     = (const float*)d_in[0];
    const float* h0    = (const float*)d_in[1];
    const float* W_ih  = (const float*)d_in[2];
    const float* b_ih  = (const float*)d_in[3];
    const float* W_hh  = (const float*)d_in[4];
    const float* b_hh  = (const float*)d_in[5];
    const float* W_out = (const float*)d_in[6];
    const float* b_out = (const float*)d_in[7];
    float* outp = (float*)d_out;

    dim3 grid(BATCH / (4 * WPB));   // 256 blocks x 4 waves x 4 seqs/wave
    dim3 block(64 * WPB);
    hipLaunchKernelGGL(rnn_kernel, grid, block, 0, stream,
                       x, h0, W_ih, b_ih, W_hh, b_hh, W_out, b_out, outp);
}